// Round 4
// baseline (221.728 us; speedup 1.0000x reference)
//
#include <hip/hip_runtime.h>
#include <hip/hip_cooperative_groups.h>
#include <math.h>

namespace cg = cooperative_groups;

#define AFWD 0.999f
#define ONE_MINUS_A (1.0f - 0.999f)
#define KCOEF (0.999f * (1.0f - 0.999f))
#define EPSV 1e-5f

typedef float floatx4 __attribute__((ext_vector_type(4)));

// Fused online-normalization forward.
// Phase A: per (chunk c, col4) local summaries with chunk-start M=0:
//   Bmu = local mu after CH steps, See = sum a^{CH-1-i} e_i^2, Te = sum e_i
// Phase B: per column, weighted Hillis-Steele scan over the C chunks:
//   M_c = A^c M0 + sum_{j<c} A^{c-1-j} bmu_j
//   w_j = KCOEF*(see_j - 2 c_eg te_j M_j + Sgg M_j^2)
//   V_c = A^c V0 + sum_{j<c} A^{c-1-j} w_j
// Phase C: replay exact recurrence from (M_c, V_c); x re-read hits L3.
__global__ __launch_bounds__(256) void
fused_cn(const float* __restrict__ x, const float* __restrict__ m,
         const float* __restrict__ var, float* __restrict__ out,
         float* __restrict__ Bmu, float* __restrict__ See,
         float* __restrict__ Te, float* __restrict__ Ms,
         float* __restrict__ Vs, int L, int L4, int C, int CH,
         float A, float c_eg, float Sgg) {
  cg::grid_group grid = cg::this_grid();
  __shared__ float sm[2 * (256 + 8)];

  int idx  = blockIdx.x * blockDim.x + threadIdx.x;
  int col4 = idx % L4;
  int c    = idx / L4;
  const floatx4* xv = (const floatx4*)x;
  int base = c * CH * L4 + col4;
  int o    = c * L4 + col4;  // float4 index into [C][L]

  // ---------------- phase A ----------------
  {
    float mu[4] = {0.f, 0.f, 0.f, 0.f};
    float s[4]  = {0.f, 0.f, 0.f, 0.f};
    float t[4]  = {0.f, 0.f, 0.f, 0.f};
#pragma unroll 4
    for (int i = 0; i < CH; ++i) {
      floatx4 v = xv[base + i * L4];
#pragma unroll
      for (int k = 0; k < 4; ++k) {
        float e = v[k] - mu[k];
        s[k] = fmaf(AFWD, s[k], e * e);
        t[k] += e;
        mu[k] = fmaf(ONE_MINUS_A, e, mu[k]);
      }
    }
    floatx4 om = {mu[0], mu[1], mu[2], mu[3]};
    floatx4 os = {s[0], s[1], s[2], s[3]};
    floatx4 ot = {t[0], t[1], t[2], t[3]};
    ((floatx4*)Bmu)[o] = om;
    ((floatx4*)See)[o] = os;
    ((floatx4*)Te)[o]  = ot;
  }

  grid.sync();

  // ---------------- phase B ----------------
  {
    int nWG       = gridDim.x;
    int colsPerWG = L / nWG;           // 1024/C * ... = L*256/(C*L4)
    int groups    = blockDim.x / C;    // parallel column lanes per WG
    int sub       = threadIdx.x / C;
    int cc        = threadIdx.x % C;
    float* smb = &sm[sub * (C + 8)];

    // Ac = A^cc (binary exponentiation, predicated)
    float Ac = 1.0f, Ap = A;
#pragma unroll
    for (int b = 0; b < 8; ++b) {
      if (cc & (1 << b)) Ac *= Ap;
      Ap *= Ap;
    }

    for (int j = 0; j < colsPerWG; j += groups) {
      int l  = blockIdx.x * colsPerWG + j + sub;
      int oo = cc * L + l;
      float bmu = Bmu[oo];
      float see = See[oo];
      float te  = Te[oo];
      float M0  = m[l];
      float V0  = var[l];

      // scan 1: mu offsets
      float p = bmu, w = A;
      for (int off = 1; off < C; off <<= 1) {
        __syncthreads(); smb[cc] = p; __syncthreads();
        if (cc >= off) p = fmaf(w, smb[cc - off], p);
        w *= w;
      }
      __syncthreads(); smb[cc] = p; __syncthreads();
      float M = fmaf(Ac, M0, cc ? smb[cc - 1] : 0.0f);

      // scan 2: variance contributions
      float wv = KCOEF * fmaf(M * M, Sgg, fmaf(-2.0f * c_eg * M, te, see));
      float q = wv; w = A;
      for (int off = 1; off < C; off <<= 1) {
        __syncthreads(); smb[cc] = q; __syncthreads();
        if (cc >= off) q = fmaf(w, smb[cc - off], q);
        w *= w;
      }
      __syncthreads(); smb[cc] = q; __syncthreads();
      float V = fmaf(Ac, V0, cc ? smb[cc - 1] : 0.0f);

      Ms[oo] = M;
      Vs[oo] = V;
    }
  }

  grid.sync();

  // ---------------- phase C ----------------
  {
    floatx4* ov = (floatx4*)out;
    floatx4 m4 = ((const floatx4*)Ms)[o];
    floatx4 v4 = ((const floatx4*)Vs)[o];
    float mu[4] = {m4[0], m4[1], m4[2], m4[3]};
    float vv[4] = {v4[0], v4[1], v4[2], v4[3]};
#pragma unroll 4
    for (int i = 0; i < CH; ++i) {
      floatx4 v = xv[base + i * L4];
      floatx4 oe;
#pragma unroll
      for (int k = 0; k < 4; ++k) {
        float d = v[k] - mu[k];
        oe[k] = d * rsqrtf(vv[k] + EPSV);
        vv[k] = fmaf(AFWD, vv[k], KCOEF * (d * d));
        mu[k] = fmaf(ONE_MINUS_A, d, mu[k]);
      }
      __builtin_nontemporal_store(oe, &ov[base + i * L4]);
    }
  }
}

extern "C" void kernel_launch(void* const* d_in, const int* in_sizes, int n_in,
                              void* d_out, int out_size, void* d_ws, size_t ws_size,
                              hipStream_t stream) {
  const float* x   = (const float*)d_in[0];
  const float* m   = (const float*)d_in[1];
  const float* var = (const float*)d_in[2];
  float* out = (float*)d_out;

  int L  = in_sizes[1];          // 4096
  int N  = in_sizes[0] / L;      // 8192
  int L4 = L / 4;

  int C = 128;
  while (C > 1 && ((size_t)5 * C * L * sizeof(float) > ws_size || (N % C) != 0))
    C >>= 1;
  int CH = N / C;

  double a = 0.999;
  float A    = (float)pow(a, (double)CH);
  float c_eg = (float)pow(a, (double)(CH - 1));
  float Sgg  = (float)(pow(a, (double)(CH - 1)) * (1.0 - pow(a, (double)CH)) / (1.0 - a));

  float* ws  = (float*)d_ws;
  size_t CL  = (size_t)C * L;
  float* Bmu = ws;
  float* See = ws + CL;
  float* Te  = ws + 2 * CL;
  float* Ms  = ws + 3 * CL;
  float* Vs  = ws + 4 * CL;

  int threadsBig = C * L4;
  dim3 grid(threadsBig / 256), block(256);
  void* args[] = {(void*)&x,   (void*)&m,   (void*)&var, (void*)&out,
                  (void*)&Bmu, (void*)&See, (void*)&Te,  (void*)&Ms,
                  (void*)&Vs,  (void*)&L,   (void*)&L4,  (void*)&C,
                  (void*)&CH,  (void*)&A,   (void*)&c_eg, (void*)&Sgg};
  hipLaunchCooperativeKernel((const void*)fused_cn, grid, block, args, 0,
                             stream);
}

// Round 5
// 103.414 us; speedup vs baseline: 2.1441x; 2.1441x over previous
//
#include <hip/hip_runtime.h>
#include <math.h>

#define AFWD 0.999f
#define ONE_MINUS_A (1.0f - 0.999f)
#define KCOEF (0.999f * (1.0f - 0.999f))
#define EPSV 1e-5f

typedef float floatx4 __attribute__((ext_vector_type(4)));

// ---------------------------------------------------------------------------
// Pass A: per (chunk c, float4-column group) local summaries with chunk-start
// M=0. Manual 4-wide load batching: 4 independent global loads issued
// back-to-back per iteration to keep >=4 loads in flight per wave (MLP).
// ---------------------------------------------------------------------------
__global__ __launch_bounds__(256) void
passA(const float* __restrict__ x, float* __restrict__ Bmu,
      float* __restrict__ See, float* __restrict__ Te, int L4, int CH) {
  int idx  = blockIdx.x * blockDim.x + threadIdx.x;
  int col4 = idx % L4;
  int c    = idx / L4;
  const floatx4* xv = (const floatx4*)x;
  int base = c * CH * L4 + col4;

  float mu[4] = {0.f, 0.f, 0.f, 0.f};
  float s[4]  = {0.f, 0.f, 0.f, 0.f};
  float t[4]  = {0.f, 0.f, 0.f, 0.f};

#pragma unroll 1
  for (int i = 0; i < CH; i += 4) {
    floatx4 v0 = xv[base + (i + 0) * L4];
    floatx4 v1 = xv[base + (i + 1) * L4];
    floatx4 v2 = xv[base + (i + 2) * L4];
    floatx4 v3 = xv[base + (i + 3) * L4];
#pragma unroll
    for (int k = 0; k < 4; ++k) {
      float e = v0[k] - mu[k];
      s[k] = fmaf(AFWD, s[k], e * e); t[k] += e;
      mu[k] = fmaf(ONE_MINUS_A, e, mu[k]);
    }
#pragma unroll
    for (int k = 0; k < 4; ++k) {
      float e = v1[k] - mu[k];
      s[k] = fmaf(AFWD, s[k], e * e); t[k] += e;
      mu[k] = fmaf(ONE_MINUS_A, e, mu[k]);
    }
#pragma unroll
    for (int k = 0; k < 4; ++k) {
      float e = v2[k] - mu[k];
      s[k] = fmaf(AFWD, s[k], e * e); t[k] += e;
      mu[k] = fmaf(ONE_MINUS_A, e, mu[k]);
    }
#pragma unroll
    for (int k = 0; k < 4; ++k) {
      float e = v3[k] - mu[k];
      s[k] = fmaf(AFWD, s[k], e * e); t[k] += e;
      mu[k] = fmaf(ONE_MINUS_A, e, mu[k]);
    }
  }

  int o = c * L4 + col4;
  floatx4 om = {mu[0], mu[1], mu[2], mu[3]};
  floatx4 os = {s[0], s[1], s[2], s[3]};
  floatx4 ot = {t[0], t[1], t[2], t[3]};
  ((floatx4*)Bmu)[o] = om;
  ((floatx4*)See)[o] = os;
  ((floatx4*)Te)[o]  = ot;
}

// ---------------------------------------------------------------------------
// Pass B: one block per column, blockDim.x == C. Two weighted Hillis-Steele
// scans over the chunk dim. Stores exclusive (chunk-start) states Ms/Vs.
// ---------------------------------------------------------------------------
__global__ void
passB_scan(const float* __restrict__ m, const float* __restrict__ var,
           const float* __restrict__ Bmu, const float* __restrict__ See,
           const float* __restrict__ Te, float* __restrict__ Ms,
           float* __restrict__ Vs, int L, int C, float A, float c_eg,
           float Sgg) {
  extern __shared__ float sm[];
  int l = blockIdx.x;
  int c = threadIdx.x;
  int o = c * L + l;

  float bmu = Bmu[o];
  float see = See[o];
  float te  = Te[o];
  float M0 = m[l];
  float V0 = var[l];

  // A^c via binary exponentiation (predicated)
  float Ac = 1.0f, Ap = A;
#pragma unroll
  for (int b = 0; b < 10; ++b) {
    if (c & (1 << b)) Ac *= Ap;
    Ap *= Ap;
  }

  // scan 1: mu offsets
  float p = bmu, w = A;
  for (int off = 1; off < C; off <<= 1) {
    __syncthreads(); sm[c] = p; __syncthreads();
    if (c >= off) p = fmaf(w, sm[c - off], p);
    w *= w;
  }
  __syncthreads(); sm[c] = p; __syncthreads();
  float M = fmaf(Ac, M0, c ? sm[c - 1] : 0.0f);

  // scan 2: variance contributions
  float wv = KCOEF * fmaf(M * M, Sgg, fmaf(-2.0f * c_eg * M, te, see));
  float q = wv; w = A;
  for (int off = 1; off < C; off <<= 1) {
    __syncthreads(); sm[c] = q; __syncthreads();
    if (c >= off) q = fmaf(w, sm[c - off], q);
    w *= w;
  }
  __syncthreads(); sm[c] = q; __syncthreads();
  float V = fmaf(Ac, V0, c ? sm[c - 1] : 0.0f);

  Ms[o] = M;
  Vs[o] = V;
}

// ---------------------------------------------------------------------------
// Pass C: replay exact recurrence from (M_c, V_c), write out. Same 4-wide
// load batching; nontemporal stores keep out from evicting x in L3.
// ---------------------------------------------------------------------------
__global__ __launch_bounds__(256) void
passC(const float* __restrict__ x, const float* __restrict__ Ms,
      const float* __restrict__ Vs, float* __restrict__ out, int L4, int CH) {
  int idx  = blockIdx.x * blockDim.x + threadIdx.x;
  int col4 = idx % L4;
  int c    = idx / L4;
  const floatx4* xv = (const floatx4*)x;
  floatx4* ov = (floatx4*)out;
  int base = c * CH * L4 + col4;

  int o = c * L4 + col4;
  floatx4 m4 = ((const floatx4*)Ms)[o];
  floatx4 v4 = ((const floatx4*)Vs)[o];
  float mu[4] = {m4[0], m4[1], m4[2], m4[3]};
  float vv[4] = {v4[0], v4[1], v4[2], v4[3]};

#pragma unroll 1
  for (int i = 0; i < CH; i += 4) {
    floatx4 v0 = xv[base + (i + 0) * L4];
    floatx4 v1 = xv[base + (i + 1) * L4];
    floatx4 v2 = xv[base + (i + 2) * L4];
    floatx4 v3 = xv[base + (i + 3) * L4];
    floatx4 o0, o1, o2, o3;
#pragma unroll
    for (int k = 0; k < 4; ++k) {
      float d = v0[k] - mu[k];
      o0[k] = d * rsqrtf(vv[k] + EPSV);
      vv[k] = fmaf(AFWD, vv[k], KCOEF * (d * d));
      mu[k] = fmaf(ONE_MINUS_A, d, mu[k]);
    }
#pragma unroll
    for (int k = 0; k < 4; ++k) {
      float d = v1[k] - mu[k];
      o1[k] = d * rsqrtf(vv[k] + EPSV);
      vv[k] = fmaf(AFWD, vv[k], KCOEF * (d * d));
      mu[k] = fmaf(ONE_MINUS_A, d, mu[k]);
    }
#pragma unroll
    for (int k = 0; k < 4; ++k) {
      float d = v2[k] - mu[k];
      o2[k] = d * rsqrtf(vv[k] + EPSV);
      vv[k] = fmaf(AFWD, vv[k], KCOEF * (d * d));
      mu[k] = fmaf(ONE_MINUS_A, d, mu[k]);
    }
#pragma unroll
    for (int k = 0; k < 4; ++k) {
      float d = v3[k] - mu[k];
      o3[k] = d * rsqrtf(vv[k] + EPSV);
      vv[k] = fmaf(AFWD, vv[k], KCOEF * (d * d));
      mu[k] = fmaf(ONE_MINUS_A, d, mu[k]);
    }
    __builtin_nontemporal_store(o0, &ov[base + (i + 0) * L4]);
    __builtin_nontemporal_store(o1, &ov[base + (i + 1) * L4]);
    __builtin_nontemporal_store(o2, &ov[base + (i + 2) * L4]);
    __builtin_nontemporal_store(o3, &ov[base + (i + 3) * L4]);
  }
}

extern "C" void kernel_launch(void* const* d_in, const int* in_sizes, int n_in,
                              void* d_out, int out_size, void* d_ws, size_t ws_size,
                              hipStream_t stream) {
  const float* x   = (const float*)d_in[0];
  const float* m   = (const float*)d_in[1];
  const float* var = (const float*)d_in[2];
  float* out = (float*)d_out;

  int L  = in_sizes[1];          // 4096
  int N  = in_sizes[0] / L;      // 8192
  int L4 = L / 4;

  // C=256 chunks: 1024 WGs (4/CU) for the big passes; CH=32 (div by 4).
  int C = 256;
  while (C > 1 && ((size_t)5 * C * L * sizeof(float) > ws_size ||
                   (N % C) != 0 || (N / C) % 4 != 0))
    C >>= 1;
  int CH = N / C;

  double a = 0.999;
  float A    = (float)pow(a, (double)CH);
  float c_eg = (float)pow(a, (double)(CH - 1));
  float Sgg  = (float)(pow(a, (double)(CH - 1)) * (1.0 - pow(a, (double)CH)) / (1.0 - a));

  float* ws  = (float*)d_ws;
  size_t CL  = (size_t)C * L;
  float* Bmu = ws;
  float* See = ws + CL;
  float* Te  = ws + 2 * CL;
  float* Ms  = ws + 3 * CL;
  float* Vs  = ws + 4 * CL;

  int threadsBig = C * L4;
  passA<<<threadsBig / 256, 256, 0, stream>>>(x, Bmu, See, Te, L4, CH);
  passB_scan<<<L, C, C * sizeof(float), stream>>>(m, var, Bmu, See, Te, Ms, Vs,
                                                  L, C, A, c_eg, Sgg);
  passC<<<threadsBig / 256, 256, 0, stream>>>(x, Ms, Vs, out, L4, CH);
}

// Round 6
// 85.260 us; speedup vs baseline: 2.6006x; 1.2129x over previous
//
#include <hip/hip_runtime.h>
#include <math.h>

#define AFWD 0.999f
#define ONE_MINUS_A (1.0f - 0.999f)
#define KCOEF (0.999f * (1.0f - 0.999f))
#define EPSV 1e-5f

typedef float floatx4 __attribute__((ext_vector_type(4)));

// ---------------------------------------------------------------------------
// Pass A (identical to the 92.4us round-3 version): per (chunk c, col4) local
// summaries with chunk-start M=0.
//   Bmu = local mu after CH steps, Te = sum e_i, See = sum a^{CH-1-i} e_i^2
// ---------------------------------------------------------------------------
__global__ __launch_bounds__(256) void
passA(const float* __restrict__ x, float* __restrict__ Bmu,
      float* __restrict__ See, float* __restrict__ Te, int L4, int CH) {
  int idx  = blockIdx.x * blockDim.x + threadIdx.x;
  int col4 = idx % L4;
  int c    = idx / L4;
  const floatx4* xv = (const floatx4*)x;
  int base = c * CH * L4 + col4;

  float mu[4] = {0.f, 0.f, 0.f, 0.f};
  float s[4]  = {0.f, 0.f, 0.f, 0.f};
  float t[4]  = {0.f, 0.f, 0.f, 0.f};

#pragma unroll 4
  for (int i = 0; i < CH; ++i) {
    floatx4 v = xv[base + i * L4];
#pragma unroll
    for (int k = 0; k < 4; ++k) {
      float e = v[k] - mu[k];
      s[k] = fmaf(AFWD, s[k], e * e);
      t[k] += e;
      mu[k] = fmaf(ONE_MINUS_A, e, mu[k]);
    }
  }

  int o = c * L4 + col4;
  floatx4 om = {mu[0], mu[1], mu[2], mu[3]};
  floatx4 os = {s[0], s[1], s[2], s[3]};
  floatx4 ot = {t[0], t[1], t[2], t[3]};
  ((floatx4*)Bmu)[o] = om;
  ((floatx4*)See)[o] = os;
  ((floatx4*)Te)[o]  = ot;
}

// ---------------------------------------------------------------------------
// Pass B1: thread = (column l, super-chunk g). Compose SUB chunk summaries
// into one super-chunk summary. All accesses coalesced over l.
//   S <- A*S + s2 - 2*c_eg*B*t2 + Sgg*B^2 ;  T <- T + t2 - G*B ;  B <- A*B+b2
// ---------------------------------------------------------------------------
__global__ __launch_bounds__(256) void
passB1(const float* __restrict__ Bmu, const float* __restrict__ See,
       const float* __restrict__ Te, float* __restrict__ Bsup,
       float* __restrict__ Ssup, float* __restrict__ Tsup, int L, int SUB,
       float A, float c_eg, float Sgg, float G) {
  int idx = blockIdx.x * blockDim.x + threadIdx.x;
  int l   = idx % L;
  int g   = idx / L;
  int base = g * SUB * L + l;

  float B = 0.f, T = 0.f, S = 0.f;
#pragma unroll 16
  for (int k = 0; k < SUB; ++k) {
    int o = base + k * L;
    float b2 = Bmu[o];
    float s2 = See[o];
    float t2 = Te[o];
    S = fmaf(A, S, fmaf(Sgg * B, B, fmaf(-2.0f * c_eg * B, t2, s2)));
    T = fmaf(-G, B, T + t2);
    B = fmaf(A, B, b2);
  }
  int o = g * L + l;
  Bsup[o] = B;
  Ssup[o] = S;
  Tsup[o] = T;
}

// ---------------------------------------------------------------------------
// Pass B2: thread = column l. Walk GS super-chunks with the real (M0,V0),
// storing super-chunk-start states. Constants at super-chunk length.
// ---------------------------------------------------------------------------
__global__ __launch_bounds__(256) void
passB2(const float* __restrict__ m, const float* __restrict__ var,
       const float* __restrict__ Bsup, const float* __restrict__ Ssup,
       const float* __restrict__ Tsup, float* __restrict__ Mg,
       float* __restrict__ Vg, int L, int GS, float Asup, float c_sup,
       float Sggsup) {
  int l = blockIdx.x * blockDim.x + threadIdx.x;
  float M = m[l];
  float V = var[l];
#pragma unroll 8
  for (int g = 0; g < GS; ++g) {
    int o = g * L + l;
    Mg[o] = M;
    Vg[o] = V;
    float b = Bsup[o];
    float s = Ssup[o];
    float t = Tsup[o];
    float sum = fmaf(M * M, Sggsup, fmaf(-2.0f * c_sup * M, t, s));
    V = fmaf(Asup, V, KCOEF * sum);
    M = fmaf(Asup, M, b);
  }
}

// ---------------------------------------------------------------------------
// Pass B3: thread = (column l, super-chunk g). From the super-chunk-start
// state, emit the SUB chunk-start states Ms/Vs. Coalesced.
// ---------------------------------------------------------------------------
__global__ __launch_bounds__(256) void
passB3(const float* __restrict__ Bmu, const float* __restrict__ See,
       const float* __restrict__ Te, const float* __restrict__ Mg,
       const float* __restrict__ Vg, float* __restrict__ Ms,
       float* __restrict__ Vs, int L, int SUB, float A, float c_eg,
       float Sgg) {
  int idx = blockIdx.x * blockDim.x + threadIdx.x;
  int l   = idx % L;
  int g   = idx / L;
  int base = g * SUB * L + l;

  float M = Mg[g * L + l];
  float V = Vg[g * L + l];
#pragma unroll 16
  for (int k = 0; k < SUB; ++k) {
    int o = base + k * L;
    Ms[o] = M;
    Vs[o] = V;
    float b = Bmu[o];
    float s = See[o];
    float t = Te[o];
    float sum = fmaf(M * M, Sgg, fmaf(-2.0f * c_eg * M, t, s));
    V = fmaf(A, V, KCOEF * sum);
    M = fmaf(A, M, b);
  }
}

// ---------------------------------------------------------------------------
// Pass C (identical to round-3): replay exact recurrence from (M_c, V_c).
// Nontemporal out stores keep x L3-resident for the re-read.
// ---------------------------------------------------------------------------
__global__ __launch_bounds__(256) void
passC(const float* __restrict__ x, const float* __restrict__ Ms,
      const float* __restrict__ Vs, float* __restrict__ out, int L4, int CH) {
  int idx  = blockIdx.x * blockDim.x + threadIdx.x;
  int col4 = idx % L4;
  int c    = idx / L4;
  const floatx4* xv = (const floatx4*)x;
  floatx4* ov = (floatx4*)out;
  int base = c * CH * L4 + col4;

  int o = c * L4 + col4;
  floatx4 m4 = ((const floatx4*)Ms)[o];
  floatx4 v4 = ((const floatx4*)Vs)[o];
  float mu[4] = {m4[0], m4[1], m4[2], m4[3]};
  float vv[4] = {v4[0], v4[1], v4[2], v4[3]};

#pragma unroll 4
  for (int i = 0; i < CH; ++i) {
    floatx4 v = xv[base + i * L4];
    floatx4 oe;
#pragma unroll
    for (int k = 0; k < 4; ++k) {
      float d = v[k] - mu[k];
      oe[k] = d * rsqrtf(vv[k] + EPSV);
      vv[k] = fmaf(AFWD, vv[k], KCOEF * (d * d));
      mu[k] = fmaf(ONE_MINUS_A, d, mu[k]);
    }
    __builtin_nontemporal_store(oe, &ov[base + i * L4]);
  }
}

extern "C" void kernel_launch(void* const* d_in, const int* in_sizes, int n_in,
                              void* d_out, int out_size, void* d_ws, size_t ws_size,
                              hipStream_t stream) {
  const float* x   = (const float*)d_in[0];
  const float* m   = (const float*)d_in[1];
  const float* var = (const float*)d_in[2];
  float* out = (float*)d_out;

  int L  = in_sizes[1];          // 4096
  int N  = in_sizes[0] / L;      // 8192
  int L4 = L / 4;

  // C=128 chunks (round-3 sweet spot), CH=64.
  int C = 128;
  while (C > 1 && ((size_t)(5 * C + 5 * (C / 16 + 1)) * L * sizeof(float) > ws_size ||
                   (N % C) != 0))
    C >>= 1;
  int CH = N / C;
  int SUB = (C >= 16) ? 16 : C;  // chunks per super-chunk
  int GS  = C / SUB;             // super-chunks

  double a = 0.999;
  // chunk-length constants
  float A    = (float)pow(a, (double)CH);
  float c_eg = (float)pow(a, (double)(CH - 1));
  float Sgg  = (float)(pow(a, (double)(CH - 1)) * (1.0 - pow(a, (double)CH)) / (1.0 - a));
  float G    = (float)((1.0 - pow(a, (double)CH)) / (1.0 - a));
  // super-chunk-length constants
  double nS = (double)SUB * CH;
  float Asup   = (float)pow(a, nS);
  float c_sup  = (float)pow(a, nS - 1.0);
  float Sggsup = (float)(pow(a, nS - 1.0) * (1.0 - pow(a, nS)) / (1.0 - a));

  float* ws  = (float*)d_ws;
  size_t CL  = (size_t)C * L;
  size_t GL  = (size_t)GS * L;
  float* Bmu  = ws;
  float* See  = ws + CL;
  float* Te   = ws + 2 * CL;
  float* Ms   = ws + 3 * CL;
  float* Vs   = ws + 4 * CL;
  float* Bsup = ws + 5 * CL;
  float* Ssup = Bsup + GL;
  float* Tsup = Bsup + 2 * GL;
  float* Mg   = Bsup + 3 * GL;
  float* Vg   = Bsup + 4 * GL;

  int threadsBig = C * L4;
  passA<<<threadsBig / 256, 256, 0, stream>>>(x, Bmu, See, Te, L4, CH);
  passB1<<<(L * GS) / 256, 256, 0, stream>>>(Bmu, See, Te, Bsup, Ssup, Tsup,
                                             L, SUB, A, c_eg, Sgg, G);
  passB2<<<L / 256, 256, 0, stream>>>(m, var, Bsup, Ssup, Tsup, Mg, Vg, L, GS,
                                      Asup, c_sup, Sggsup);
  passB3<<<(L * GS) / 256, 256, 0, stream>>>(Bmu, See, Te, Mg, Vg, Ms, Vs,
                                             L, SUB, A, c_eg, Sgg);
  passC<<<threadsBig / 256, 256, 0, stream>>>(x, Ms, Vs, out, L4, CH);
}

// Round 7
// 84.417 us; speedup vs baseline: 2.6266x; 1.0100x over previous
//
#include <hip/hip_runtime.h>
#include <math.h>

#define AFWD 0.999f
#define ONE_MINUS_A (1.0f - 0.999f)
#define KCOEF (0.999f * (1.0f - 0.999f))
#define EPSV 1e-5f

typedef float floatx4 __attribute__((ext_vector_type(4)));

// ---------------------------------------------------------------------------
// Pass A: per (chunk c, col4) local summaries with chunk-start M=0.
//   Bmu = local mu after CH steps, Te = sum e_i, See = sum a^{CH-1-i} e_i^2
// C=256 -> 1024 WGs (4/CU) for latency hiding.
// ---------------------------------------------------------------------------
__global__ __launch_bounds__(256) void
passA(const float* __restrict__ x, float* __restrict__ Bmu,
      float* __restrict__ See, float* __restrict__ Te, int L4, int CH) {
  int idx  = blockIdx.x * blockDim.x + threadIdx.x;
  int col4 = idx % L4;
  int c    = idx / L4;
  const floatx4* xv = (const floatx4*)x;
  int base = c * CH * L4 + col4;

  float mu[4] = {0.f, 0.f, 0.f, 0.f};
  float s[4]  = {0.f, 0.f, 0.f, 0.f};
  float t[4]  = {0.f, 0.f, 0.f, 0.f};

#pragma unroll 4
  for (int i = 0; i < CH; ++i) {
    floatx4 v = xv[base + i * L4];
#pragma unroll
    for (int k = 0; k < 4; ++k) {
      float e = v[k] - mu[k];
      s[k] = fmaf(AFWD, s[k], e * e);
      t[k] += e;
      mu[k] = fmaf(ONE_MINUS_A, e, mu[k]);
    }
  }

  int o = c * L4 + col4;
  floatx4 om = {mu[0], mu[1], mu[2], mu[3]};
  floatx4 os = {s[0], s[1], s[2], s[3]};
  floatx4 ot = {t[0], t[1], t[2], t[3]};
  ((floatx4*)Bmu)[o] = om;
  ((floatx4*)See)[o] = os;
  ((floatx4*)Te)[o]  = ot;
}

// ---------------------------------------------------------------------------
// Pass B1: thread = (column l, super-chunk g). Compose SUB chunk summaries
// into one super-chunk summary. Coalesced over l.
// ---------------------------------------------------------------------------
__global__ __launch_bounds__(256) void
passB1(const float* __restrict__ Bmu, const float* __restrict__ See,
       const float* __restrict__ Te, float* __restrict__ Bsup,
       float* __restrict__ Ssup, float* __restrict__ Tsup, int L, int SUB,
       float A, float c_eg, float Sgg, float G) {
  int idx = blockIdx.x * blockDim.x + threadIdx.x;
  int l   = idx % L;
  int g   = idx / L;
  int base = g * SUB * L + l;

  float B = 0.f, T = 0.f, S = 0.f;
#pragma unroll 16
  for (int k = 0; k < SUB; ++k) {
    int o = base + k * L;
    float b2 = Bmu[o];
    float s2 = See[o];
    float t2 = Te[o];
    S = fmaf(A, S, fmaf(Sgg * B, B, fmaf(-2.0f * c_eg * B, t2, s2)));
    T = fmaf(-G, B, T + t2);
    B = fmaf(A, B, b2);
  }
  int o = g * L + l;
  Bsup[o] = B;
  Ssup[o] = S;
  Tsup[o] = T;
}

// ---------------------------------------------------------------------------
// Pass B2: thread = column l. Walk GS super-chunks with the real (M0,V0).
// ---------------------------------------------------------------------------
__global__ __launch_bounds__(256) void
passB2(const float* __restrict__ m, const float* __restrict__ var,
       const float* __restrict__ Bsup, const float* __restrict__ Ssup,
       const float* __restrict__ Tsup, float* __restrict__ Mg,
       float* __restrict__ Vg, int L, int GS, float Asup, float c_sup,
       float Sggsup) {
  int l = blockIdx.x * blockDim.x + threadIdx.x;
  float M = m[l];
  float V = var[l];
#pragma unroll 16
  for (int g = 0; g < GS; ++g) {
    int o = g * L + l;
    Mg[o] = M;
    Vg[o] = V;
    float b = Bsup[o];
    float s = Ssup[o];
    float t = Tsup[o];
    float sum = fmaf(M * M, Sggsup, fmaf(-2.0f * c_sup * M, t, s));
    V = fmaf(Asup, V, KCOEF * sum);
    M = fmaf(Asup, M, b);
  }
}

// ---------------------------------------------------------------------------
// Pass B3: thread = (column l, super-chunk g). Emit SUB chunk-start states.
// ---------------------------------------------------------------------------
__global__ __launch_bounds__(256) void
passB3(const float* __restrict__ Bmu, const float* __restrict__ See,
       const float* __restrict__ Te, const float* __restrict__ Mg,
       const float* __restrict__ Vg, float* __restrict__ Ms,
       float* __restrict__ Vs, int L, int SUB, float A, float c_eg,
       float Sgg) {
  int idx = blockIdx.x * blockDim.x + threadIdx.x;
  int l   = idx % L;
  int g   = idx / L;
  int base = g * SUB * L + l;

  float M = Mg[g * L + l];
  float V = Vg[g * L + l];
#pragma unroll 16
  for (int k = 0; k < SUB; ++k) {
    int o = base + k * L;
    Ms[o] = M;
    Vs[o] = V;
    float b = Bmu[o];
    float s = See[o];
    float t = Te[o];
    float sum = fmaf(M * M, Sgg, fmaf(-2.0f * c_eg * M, t, s));
    V = fmaf(A, V, KCOEF * sum);
    M = fmaf(A, M, b);
  }
}

// ---------------------------------------------------------------------------
// Pass C: replay exact recurrence from (M_c, V_c). NT out stores keep x
// L3-resident for the re-read.
// ---------------------------------------------------------------------------
__global__ __launch_bounds__(256) void
passC(const float* __restrict__ x, const float* __restrict__ Ms,
      const float* __restrict__ Vs, float* __restrict__ out, int L4, int CH) {
  int idx  = blockIdx.x * blockDim.x + threadIdx.x;
  int col4 = idx % L4;
  int c    = idx / L4;
  const floatx4* xv = (const floatx4*)x;
  floatx4* ov = (floatx4*)out;
  int base = c * CH * L4 + col4;

  int o = c * L4 + col4;
  floatx4 m4 = ((const floatx4*)Ms)[o];
  floatx4 v4 = ((const floatx4*)Vs)[o];
  float mu[4] = {m4[0], m4[1], m4[2], m4[3]};
  float vv[4] = {v4[0], v4[1], v4[2], v4[3]};

#pragma unroll 4
  for (int i = 0; i < CH; ++i) {
    floatx4 v = xv[base + i * L4];
    floatx4 oe;
#pragma unroll
    for (int k = 0; k < 4; ++k) {
      float d = v[k] - mu[k];
      oe[k] = d * rsqrtf(vv[k] + EPSV);
      vv[k] = fmaf(AFWD, vv[k], KCOEF * (d * d));
      mu[k] = fmaf(ONE_MINUS_A, d, mu[k]);
    }
    __builtin_nontemporal_store(oe, &ov[base + i * L4]);
  }
}

extern "C" void kernel_launch(void* const* d_in, const int* in_sizes, int n_in,
                              void* d_out, int out_size, void* d_ws, size_t ws_size,
                              hipStream_t stream) {
  const float* x   = (const float*)d_in[0];
  const float* m   = (const float*)d_in[1];
  const float* var = (const float*)d_in[2];
  float* out = (float*)d_out;

  int L  = in_sizes[1];          // 4096
  int N  = in_sizes[0] / L;      // 8192
  int L4 = L / 4;

  // C=256 chunks -> 1024 WGs (4/CU) for the big passes; CH=32.
  int C = 256;
  while (C > 1 &&
         ((size_t)(5 * C + 5 * (C / 16 + 1)) * L * sizeof(float) > ws_size ||
          (N % C) != 0))
    C >>= 1;
  int CH = N / C;
  int SUB = (C >= 16) ? 16 : C;
  int GS  = C / SUB;

  double a = 0.999;
  float A    = (float)pow(a, (double)CH);
  float c_eg = (float)pow(a, (double)(CH - 1));
  float Sgg  = (float)(pow(a, (double)(CH - 1)) * (1.0 - pow(a, (double)CH)) / (1.0 - a));
  float G    = (float)((1.0 - pow(a, (double)CH)) / (1.0 - a));
  double nS = (double)SUB * CH;
  float Asup   = (float)pow(a, nS);
  float c_sup  = (float)pow(a, nS - 1.0);
  float Sggsup = (float)(pow(a, nS - 1.0) * (1.0 - pow(a, nS)) / (1.0 - a));

  float* ws  = (float*)d_ws;
  size_t CL  = (size_t)C * L;
  size_t GL  = (size_t)GS * L;
  float* Bmu  = ws;
  float* See  = ws + CL;
  float* Te   = ws + 2 * CL;
  float* Ms   = ws + 3 * CL;
  float* Vs   = ws + 4 * CL;
  float* Bsup = ws + 5 * CL;
  float* Ssup = Bsup + GL;
  float* Tsup = Bsup + 2 * GL;
  float* Mg   = Bsup + 3 * GL;
  float* Vg   = Bsup + 4 * GL;

  int threadsBig = C * L4;
  passA<<<threadsBig / 256, 256, 0, stream>>>(x, Bmu, See, Te, L4, CH);
  passB1<<<(L * GS) / 256, 256, 0, stream>>>(Bmu, See, Te, Bsup, Ssup, Tsup,
                                             L, SUB, A, c_eg, Sgg, G);
  passB2<<<L / 256, 256, 0, stream>>>(m, var, Bsup, Ssup, Tsup, Mg, Vg, L, GS,
                                      Asup, c_sup, Sggsup);
  passB3<<<(L * GS) / 256, 256, 0, stream>>>(Bmu, See, Te, Mg, Vg, Ms, Vs,
                                             L, SUB, A, c_eg, Sgg);
  passC<<<threadsBig / 256, 256, 0, stream>>>(x, Ms, Vs, out, L4, CH);
}